// Round 1
// 489.215 us; speedup vs baseline: 1.4981x; 1.4981x over previous
//
#include <hip/hip_runtime.h>
#include <cmath>

// Problem constants
#define NPTS   1000000
#define GXD    116
#define GYD    87
#define NB     4
#define NSEG   40368          // NB*GXD*GYD
#define OUTN   25690112       // 4*128*224*224

// workspace layout in 4-byte elements
#define OFF_INV    0          // NPTS int
#define OFF_SORT   1000000    // NPTS int
#define OFF_CNT    2000000    // NSEG int
#define OFF_OFFS   2050000    // NSEG+1 int
#define OFF_FILL   2100000    // NSEG int
#define OFF_STATS  2150000    // float: [0..14) S-moments; BN1 stats sharded 16x:
                              //   sum[ch]  at 16 + 512*cpy + ch
                              //   ssq[ch]  at 16 + 512*cpy + 256 + ch   (cpy 0..15)
#define OFF_BN0    2158500    // float: [0..32) a0, [32..64) b0'
#define OFF_MINP   2160000    // NSEG*128 float
#define OFF_MAXP   7350000    // NSEG*128 float
#define OFF_DENSE  12550000   // 4*128*87*116 float

typedef __attribute__((ext_vector_type(8))) short short8v;   // 8 bf16 (4 VGPRs)
typedef __attribute__((ext_vector_type(4))) float float4v;   // MFMA C/D

union Frag {
  unsigned u[4];
  int4 i4;
  short8v v;
};

__device__ __forceinline__ float fastrcp(float x) { return __builtin_amdgcn_rcpf(x); }
__device__ __forceinline__ float swishf(float z) { return z * fastrcp(1.0f + __expf(-z)); }
__device__ __forceinline__ unsigned fbits(float x) { return __builtin_bit_cast(unsigned, x); }
__device__ __forceinline__ float ubf(unsigned x) { return __builtin_bit_cast(float, x); }

// Split a pair of f32 into packed bf16 hi (truncated) and bf16 lo (residual, truncated).
// 3-term MFMA (hi*hi + hi*lo + lo*hi) then carries ~2^-16 relative error — fp32-fidelity
// for this problem's tolerance.
__device__ __forceinline__ void bfsplit2(float x0, float x1, unsigned& hi, unsigned& lo) {
  unsigned h0b = fbits(x0) & 0xffff0000u;
  unsigned h1b = fbits(x1) & 0xffff0000u;
  hi = (h0b >> 16) | h1b;
  float l0 = x0 - ubf(h0b), l1 = x1 - ubf(h1b);
  lo = (fbits(l0) >> 16) | (fbits(l1) & 0xffff0000u);
}

__global__ __launch_bounds__(256) void k_init(int* __restrict__ cnt, int* __restrict__ fill,
                                              float* __restrict__ stats) {
  int i = blockIdx.x * 256 + threadIdx.x;
  if (i < NSEG) { cnt[i] = 0; fill[i] = 0; }
  if (i < 8224) stats[i] = 0.0f;
}

// Pass 1: inv + cnt + feats moment matrix (S1[4], upper-tri S2[10]).
__global__ __launch_bounds__(256) void k_point1(const float* __restrict__ pts,
                                                int* __restrict__ inv,
                                                int* __restrict__ cnt,
                                                float* __restrict__ Sg) {
  float acc[14];
  #pragma unroll
  for (int q = 0; q < 14; ++q) acc[q] = 0.0f;
  const float i346 = 1.0f / 346.0f, i260 = 1.0f / 260.0f, i200 = 1.0f / 200.0f;
  const int stride = gridDim.x * 256;
  for (int i = blockIdx.x * 256 + threadIdx.x; i < NPTS; i += stride) {
    float b = pts[i*5+0], x = pts[i*5+1], y = pts[i*5+2], t = pts[i*5+3], p = pts[i*5+4];
    // exact IEEE divide here: floor(RN(x/3)) must match jax at cell boundaries
    int cx = (int)floorf(x / 3.0f);
    int cy = (int)floorf(y / 3.0f);
    int bi = (int)b;
    if (cx >= 0 && cx < GXD && cy >= 0 && cy < GYD && bi >= 0 && bi < NB) {
      int iv = (bi*GXD + cx)*GYD + cy;
      inv[i] = iv;
      atomicAdd(&cnt[iv], 1);
    } else {
      inv[i] = -1;
    }
    float f0 = x*i346, f1 = y*i260, f2 = t*i200, f3 = p;
    acc[0]+=f0; acc[1]+=f1; acc[2]+=f2; acc[3]+=f3;
    acc[4]+=f0*f0; acc[5]+=f0*f1; acc[6]+=f0*f2; acc[7]+=f0*f3;
    acc[8]+=f1*f1; acc[9]+=f1*f2; acc[10]+=f1*f3;
    acc[11]+=f2*f2; acc[12]+=f2*f3; acc[13]+=f3*f3;
  }
  __shared__ float lds[4*14];
  int lane = threadIdx.x & 63, wave = threadIdx.x >> 6;
  #pragma unroll
  for (int q = 0; q < 14; ++q) {
    float v = acc[q];
    #pragma unroll
    for (int d = 32; d > 0; d >>= 1) v += __shfl_down(v, d, 64);
    if (lane == 0) lds[wave*14 + q] = v;
  }
  __syncthreads();
  if (threadIdx.x < 14) {
    float v = lds[threadIdx.x] + lds[14+threadIdx.x] + lds[28+threadIdx.x] + lds[42+threadIdx.x];
    atomicAdd(&Sg[threadIdx.x], v);
  }
}

// BN0 coefficients + exclusive scan of cnt -> offs (single block, serial chunks).
__global__ __launch_bounds__(1024) void k_scan(const int* __restrict__ cnt,
                                               int* __restrict__ offs,
                                               const float* __restrict__ S,
                                               float* __restrict__ bn0,
                                               const float* __restrict__ W0,
                                               const float* __restrict__ g0,
                                               const float* __restrict__ b0) {
  __shared__ int wtot[16];
  const int tid = threadIdx.x;
  if (tid < 32) {
    const float invN = 1.0f / (float)NPTS;
    float w0 = W0[tid], w1 = W0[32+tid], w2 = W0[64+tid], w3 = W0[96+tid];
    float mu = (S[0]*w0 + S[1]*w1 + S[2]*w2 + S[3]*w3) * invN;
    float e2 = (S[4]*w0*w0 + S[8]*w1*w1 + S[11]*w2*w2 + S[13]*w3*w3
              + 2.0f*(S[5]*w0*w1 + S[6]*w0*w2 + S[7]*w0*w3
                    + S[9]*w1*w2 + S[10]*w1*w3 + S[12]*w2*w3)) * invN;
    float var = e2 - mu*mu;
    float a = rsqrtf(var + 1e-3f) * g0[tid];
    bn0[tid] = a;
    bn0[32+tid] = b0[tid] - mu*a;
  }
  const int CH = 40;                      // 1024*40 = 40960 >= NSEG
  const int base = tid * CH;
  int loc[CH];
  int s = 0;
  #pragma unroll
  for (int i = 0; i < CH; ++i) {
    int v = (base + i < NSEG) ? cnt[base + i] : 0;
    loc[i] = s; s += v;
  }
  int inc = s;
  const int lane = tid & 63, wv = tid >> 6;
  #pragma unroll
  for (int d = 1; d < 64; d <<= 1) {
    int t = __shfl_up(inc, d, 64);
    if (lane >= d) inc += t;
  }
  if (lane == 63) wtot[wv] = inc;
  __syncthreads();
  if (tid == 0) {
    int run = 0;
    #pragma unroll
    for (int w = 0; w < 16; ++w) { int t = wtot[w]; wtot[w] = run; run += t; }
    offs[NSEG] = run;
  }
  __syncthreads();
  int ex = wtot[wv] + (inc - s);          // exclusive prefix for this thread
  #pragma unroll
  for (int i = 0; i < CH; ++i)
    if (base + i < NSEG) offs[base + i] = ex + loc[i];
}

// Counting-sort scatter: point ids grouped by segment
__global__ __launch_bounds__(256) void k_scatter(const int* __restrict__ inv,
                                                 const int* __restrict__ offs,
                                                 int* __restrict__ fill,
                                                 int* __restrict__ sortedIdx) {
  int i = blockIdx.x * 256 + threadIdx.x;
  if (i >= NPTS) return;
  int iv = inv[i];
  if (iv < 0) return;
  int pos = offs[iv] + atomicAdd(&fill[iv], 1);
  sortedIdx[pos] = i;
}

// Main segment pass, MFMA version. One wave per segment, 16-point groups.
// Lane l (q=l>>4, r=l&15):
//   A-fragment (mfma_f32_16x16x32_bf16): lane holds A[r][8q+j]  -> compute h0 of
//     point r, channels 8q..8q+7 directly in fragment layout.
//   B-fragment tile t: lane holds W1[8q+j][16t+r]. Bhi in VGPRs, Blo + bottom-W1
//     (hi/lo) in LDS.
//   D-fragment: lane holds z[point 4q+i][channel 16t+r] -> per-lane min/max/sum/ssq,
//     reduced across q via shfl_xor(16/32).
// Precision: 3-term bf16 split (hi*hi + hi*lo + lo*hi) ~ 2^-16 rel error.
// Pad slots replicate point 0 (min/max-safe); stats gated in tail group only.
// c_s = m0 @ W1bot via MFMA with all 16 A-rows = m0 (every acc reg = c, no bcast).
__global__ __launch_bounds__(256) void k_seg(const float* __restrict__ pts,
                                             const int* __restrict__ sortedIdx,
                                             const int* __restrict__ offs,
                                             const float* __restrict__ W0,
                                             const float* __restrict__ bn0,
                                             const float* __restrict__ W1g,
                                             float* __restrict__ minp,
                                             float* __restrict__ maxp,
                                             float* __restrict__ stats) {
  __shared__ int4 bloS[8][64];    // W1 top, lo fragments (8 KB)
  __shared__ int4 bbHiS[8][64];   // W1 bottom, hi fragments (8 KB)
  __shared__ int4 bbLoS[8][64];   // W1 bottom, lo fragments (8 KB)
  const int tid = threadIdx.x;
  const int wave = tid >> 6, lane = tid & 63;
  const int q = lane >> 4, r = lane & 15;

  // per-lane BN0-folded W0 coefficients for channels 8q+j
  const float i346 = 1.0f/346.0f, i260 = 1.0f/260.0f, i200 = 1.0f/200.0f;
  float wax[8], way[8], wat[8], wap[8], wc0[8];
  #pragma unroll
  for (int j = 0; j < 8; ++j) {
    int ch = 8*q + j;
    float a0 = bn0[ch];
    wax[j] = W0[ch]    * (i346 * a0);
    way[j] = W0[32+ch] * (i260 * a0);
    wat[j] = W0[64+ch] * (i200 * a0);
    wap[j] = W0[96+ch] * a0;
    wc0[j] = bn0[32+ch];
  }

  // B fragments
  short8v Bhi[8];
  #pragma unroll
  for (int t = 0; t < 8; ++t) {
    Frag fh, fl;
    #pragma unroll
    for (int d = 0; d < 4; ++d) {
      float w0v = W1g[(8*q + 2*d    )*128 + 16*t + r];
      float w1v = W1g[(8*q + 2*d + 1)*128 + 16*t + r];
      bfsplit2(w0v, w1v, fh.u[d], fl.u[d]);
    }
    Bhi[t] = fh.v;
    if (wave == 0) {
      bloS[t][lane] = fl.i4;
      Frag gh, gl;
      #pragma unroll
      for (int d = 0; d < 4; ++d) {
        float w0v = W1g[(32 + 8*q + 2*d    )*128 + 16*t + r];
        float w1v = W1g[(32 + 8*q + 2*d + 1)*128 + 16*t + r];
        bfsplit2(w0v, w1v, gh.u[d], gl.u[d]);
      }
      bbHiS[t][lane] = gh.i4;
      bbLoS[t][lane] = gl.i4;
    }
  }
  __syncthreads();

  float gsum[8], gssq[8];
  #pragma unroll
  for (int t = 0; t < 8; ++t) { gsum[t] = 0.f; gssq[t] = 0.f; }

  const int nw = gridDim.x * 4;
  for (int s = blockIdx.x*4 + wave; s < NSEG; s += nw) {
    const int off = offs[s], pend = offs[s+1];
    const int n = pend - off;
    if (n <= 0) continue;
    const int ngroups = (n + 15) >> 4;
    float m0r[8], mn[8], mx[8], su[8], sq[8];
    #pragma unroll
    for (int t = 0; t < 8; ++t) {
      m0r[t] = -1e30f; mn[t] = 1e30f; mx[t] = -1e30f; su[t] = 0.f; sq[t] = 0.f;
    }
    // preload group 0 point (slot r; pad slots replicate point 0)
    int ip = sortedIdx[off + (r < n ? r : 0)];
    float px = pts[ip*5+1], py = pts[ip*5+2], ptt = pts[ip*5+3], ppl = pts[ip*5+4];
    for (int g = 0; g < ngroups; ++g) {
      // prefetch next group's point while we compute (hides HBM/L2 latency)
      int slot1 = (g+1)*16 + r;
      int ip1 = sortedIdx[off + (slot1 < n ? slot1 : 0)];
      float nx = pts[ip1*5+1], ny = pts[ip1*5+2], ntt = pts[ip1*5+3], npl = pts[ip1*5+4];

      // h0 for point r, channels 8q..8q+7 (exact A-fragment layout)
      float h0v[8];
      #pragma unroll
      for (int j = 0; j < 8; ++j) {
        float pre = fmaf(px, wax[j], fmaf(py, way[j], fmaf(ptt, wat[j], fmaf(ppl, wap[j], wc0[j]))));
        float h = swishf(pre);
        h0v[j] = h;
        m0r[j] = fmaxf(m0r[j], h);
      }
      Frag ah, al;
      #pragma unroll
      for (int d = 0; d < 4; ++d)
        bfsplit2(h0v[2*d], h0v[2*d+1], ah.u[d], al.u[d]);

      const int rem = n - g*16;
      #pragma unroll
      for (int t = 0; t < 8; ++t) {
        Frag fb; fb.i4 = bloS[t][lane];
        float4v acc = {0.f, 0.f, 0.f, 0.f};
        acc = __builtin_amdgcn_mfma_f32_16x16x32_bf16(ah.v, Bhi[t], acc, 0, 0, 0);
        acc = __builtin_amdgcn_mfma_f32_16x16x32_bf16(ah.v, fb.v,   acc, 0, 0, 0);
        acc = __builtin_amdgcn_mfma_f32_16x16x32_bf16(al.v, Bhi[t], acc, 0, 0, 0);
        if (rem >= 16) {
          #pragma unroll
          for (int i = 0; i < 4; ++i) {
            float z = acc[i];
            mn[t] = fminf(mn[t], z); mx[t] = fmaxf(mx[t], z);
            su[t] += z; sq[t] = fmaf(z, z, sq[t]);
          }
        } else {
          // tail: min/max always safe (pad rows hold a real point's z);
          // sums gated per row (row = 4q+i)
          #pragma unroll
          for (int i = 0; i < 4; ++i) {
            float z = acc[i];
            mn[t] = fminf(mn[t], z); mx[t] = fmaxf(mx[t], z);
            float zz = (4*q + i < rem) ? z : 0.f;
            su[t] += zz; sq[t] = fmaf(zz, zz, sq[t]);
          }
        }
      }
      px = nx; py = ny; ptt = ntt; ppl = npl;
    }

    // m0 = segment max of h0: reduce over r (bits 0..3 of lane)
    #pragma unroll
    for (int j = 0; j < 8; ++j) {
      float v = m0r[j];
      v = fmaxf(v, __shfl_xor(v, 1, 64));
      v = fmaxf(v, __shfl_xor(v, 2, 64));
      v = fmaxf(v, __shfl_xor(v, 4, 64));
      v = fmaxf(v, __shfl_xor(v, 8, 64));
      m0r[j] = v;
    }
    // c = m0 @ W1bot via MFMA; A rows all equal m0 -> every D reg holds c[16t+r]
    Frag mh, ml;
    #pragma unroll
    for (int d = 0; d < 4; ++d)
      bfsplit2(m0r[2*d], m0r[2*d+1], mh.u[d], ml.u[d]);
    float c[8];
    #pragma unroll
    for (int t = 0; t < 8; ++t) {
      Frag gh; gh.i4 = bbHiS[t][lane];
      Frag gl; gl.i4 = bbLoS[t][lane];
      float4v cacc = {0.f, 0.f, 0.f, 0.f};
      cacc = __builtin_amdgcn_mfma_f32_16x16x32_bf16(mh.v, gh.v, cacc, 0, 0, 0);
      cacc = __builtin_amdgcn_mfma_f32_16x16x32_bf16(mh.v, gl.v, cacc, 0, 0, 0);
      cacc = __builtin_amdgcn_mfma_f32_16x16x32_bf16(ml.v, gh.v, cacc, 0, 0, 0);
      c[t] = cacc[0];
    }
    // combine across q-groups (xor 16, 32) -> full-segment values on all lanes
    #pragma unroll
    for (int t = 0; t < 8; ++t) {
      mn[t] = fminf(mn[t], __shfl_xor(mn[t], 16, 64));
      mn[t] = fminf(mn[t], __shfl_xor(mn[t], 32, 64));
      mx[t] = fmaxf(mx[t], __shfl_xor(mx[t], 16, 64));
      mx[t] = fmaxf(mx[t], __shfl_xor(mx[t], 32, 64));
      su[t] += __shfl_xor(su[t], 16, 64);
      su[t] += __shfl_xor(su[t], 32, 64);
      sq[t] += __shfl_xor(sq[t], 16, 64);
      sq[t] += __shfl_xor(sq[t], 32, 64);
      float nf = (float)n;
      gsum[t] += su[t] + nf * c[t];
      gssq[t] += sq[t] + 2.0f*c[t]*su[t] + nf*c[t]*c[t];
    }
    if (lane < 16) {
      #pragma unroll
      for (int t = 0; t < 8; ++t) {
        minp[s*128 + 16*t + r] = mn[t] + c[t];
        maxp[s*128 + 16*t + r] = mx[t] + c[t];
      }
    }
  }
  // sharded stats accumulation (16 copies) to bound per-cacheline atomic serialization
  if (lane < 16) {
    const int cpy = ((blockIdx.x << 2) | wave) & 15;
    float* sb = stats + 16 + 512*cpy;
    #pragma unroll
    for (int t = 0; t < 8; ++t) {
      atomicAdd(&sb[16*t + r], gsum[t]);
      atomicAdd(&sb[256 + 16*t + r], gssq[t]);
    }
  }
}

// Dense grid: BN1 + swish at pre-extremes (exact segment_max via swish
// quasiconvexity), LDS transpose for coalesced writes.
__global__ __launch_bounds__(256) void k_dense(const float* __restrict__ minp,
                                               const float* __restrict__ maxp,
                                               const int* __restrict__ offs,
                                               const float* __restrict__ stats,
                                               const float* __restrict__ g1,
                                               const float* __restrict__ b1,
                                               float* __restrict__ dense) {
  __shared__ float tile[116*129];
  __shared__ float aS[128], bS[128];
  const int b = blockIdx.x / GYD;
  const int gy = blockIdx.x % GYD;
  const int tid = threadIdx.x;
  if (tid < 128) {
    const float invN = 1.0f / (float)NPTS;
    float s = 0.f, q2 = 0.f;
    #pragma unroll
    for (int cpy = 0; cpy < 16; ++cpy) {
      s  += stats[16 + 512*cpy + tid];
      q2 += stats[16 + 512*cpy + 256 + tid];
    }
    float mu = s * invN;
    float var = q2 * invN - mu*mu;
    float a = rsqrtf(var + 1e-3f) * g1[tid];
    aS[tid] = a;
    bS[tid] = b1[tid] - mu*a;
  }
  __syncthreads();
  for (int i = tid; i < 116*128; i += 256) {
    int gx = i >> 7, c = i & 127;
    int s = (b*GXD + gx)*GYD + gy;
    float m = 0.0f;
    if (offs[s+1] - offs[s] > 0) {
      float zl = fmaf(aS[c], minp[s*128+c], bS[c]);
      float zh = fmaf(aS[c], maxp[s*128+c], bS[c]);
      m = fmaxf(swishf(zl), swishf(zh));
    }
    tile[gx*129 + c] = m;
  }
  __syncthreads();
  for (int i = tid; i < 128*116; i += 256) {
    int c = i / 116, gx = i % 116;
    dense[((b*128 + c)*GYD + gy)*GXD + gx] = tile[gx*129 + c];
  }
}

// Bilinear resize (align-corners), dense (4,128,87,116) -> out (4,128,224,224),
// float4 stores (224 = 56*4).
__global__ __launch_bounds__(256) void k_resize(const float* __restrict__ dense,
                                                float* __restrict__ out) {
  int o4 = blockIdx.x * 256 + threadIdx.x;
  if (o4 >= OUTN/4) return;
  int xq = o4 % 56;
  int r = o4 / 56;
  int yo = r % 224;
  int bc = r / 224;
  float ys = (float)yo * (86.0f/223.0f);
  float yf = floorf(ys); int y0 = (int)yf; int y1 = min(y0+1, 86); float wy = ys - yf;
  const float* d0 = dense + bc*(87*116) + y0*116;
  const float* d1 = dense + bc*(87*116) + y1*116;
  float res[4];
  #pragma unroll
  for (int g = 0; g < 4; ++g) {
    int xo = xq*4 + g;
    float xs = (float)xo * (115.0f/223.0f);
    float xf = floorf(xs); int x0 = (int)xf; int x1 = min(x0+1, 115); float wx = xs - xf;
    float c0v = d0[x0]*(1.0f-wy) + d1[x0]*wy;
    float c1v = d0[x1]*(1.0f-wy) + d1[x1]*wy;
    res[g] = c0v*(1.0f-wx) + c1v*wx;
  }
  *(float4*)&out[o4*4] = make_float4(res[0], res[1], res[2], res[3]);
}

extern "C" void kernel_launch(void* const* d_in, const int* in_sizes, int n_in,
                              void* d_out, int out_size, void* d_ws, size_t ws_size,
                              hipStream_t stream) {
  // setup_inputs order: fus(unused), points, W0, g0, b0, W1, g1, b1
  const float* pts = (const float*)d_in[1];
  const float* W0  = (const float*)d_in[2];
  const float* g0  = (const float*)d_in[3];
  const float* b0  = (const float*)d_in[4];
  const float* W1  = (const float*)d_in[5];
  const float* g1  = (const float*)d_in[6];
  const float* b1  = (const float*)d_in[7];
  float* out = (float*)d_out;
  int*   wsi = (int*)d_ws;
  float* wsf = (float*)d_ws;

  k_init<<<158, 256, 0, stream>>>(wsi+OFF_CNT, wsi+OFF_FILL, wsf+OFF_STATS);
  k_point1<<<256, 256, 0, stream>>>(pts, wsi+OFF_INV, wsi+OFF_CNT, wsf+OFF_STATS);
  k_scan<<<1, 1024, 0, stream>>>(wsi+OFF_CNT, wsi+OFF_OFFS, wsf+OFF_STATS, wsf+OFF_BN0, W0, g0, b0);
  k_scatter<<<(NPTS+255)/256, 256, 0, stream>>>(wsi+OFF_INV, wsi+OFF_OFFS, wsi+OFF_FILL, wsi+OFF_SORT);
  k_seg<<<2048, 256, 0, stream>>>(pts, wsi+OFF_SORT, wsi+OFF_OFFS, W0, wsf+OFF_BN0, W1,
                                  wsf+OFF_MINP, wsf+OFF_MAXP, wsf+OFF_STATS);
  k_dense<<<NB*GYD, 256, 0, stream>>>(wsf+OFF_MINP, wsf+OFF_MAXP, wsi+OFF_OFFS, wsf+OFF_STATS,
                                      g1, b1, wsf+OFF_DENSE);
  k_resize<<<OUTN/4/256, 256, 0, stream>>>(wsf+OFF_DENSE, out);
}

// Round 2
// 430.860 us; speedup vs baseline: 1.7010x; 1.1354x over previous
//
#include <hip/hip_runtime.h>
#include <cmath>

// Problem constants
#define NPTS   1000000
#define GXD    116
#define GYD    87
#define NB     4
#define NSEG   40368          // NB*GXD*GYD
#define OUTN   25690112       // 4*128*224*224

// workspace layout in 4-byte elements
#define OFF_INV    0          // NPTS int
#define OFF_CNT    2000000    // NSEG int
#define OFF_OFFS   2050000    // NSEG+1 int
#define OFF_FILL   2100000    // NSEG int
#define OFF_STATS  2150000    // float: [0..14) S-moments; BN1 stats sharded 16x:
                              //   sum[ch]  at 16 + 512*cpy + ch
                              //   ssq[ch]  at 16 + 512*cpy + 256 + ch   (cpy 0..15)
#define OFF_BN0    2158500    // float: [0..32) a0, [32..64) b0'
#define OFF_FRAG   2158592    // int4[2048]: FBH | FBL | FGH | FGL  (each [8][64])
#define OFF_MINP   2170000    // float [128][NSEG]  (channel-major)
#define OFF_MAXP   7340000    // float [128][NSEG]
#define OFF_SPTS   12510000   // float4[NPTS] sorted point payloads (x,y,t,p)

typedef __attribute__((ext_vector_type(8))) short short8v;   // 8 bf16 (4 VGPRs)
typedef __attribute__((ext_vector_type(4))) float float4v;   // MFMA C/D

union Frag {
  unsigned u[4];
  int4 i4;
  short8v v;
};

__device__ __forceinline__ float fastrcp(float x) { return __builtin_amdgcn_rcpf(x); }
__device__ __forceinline__ float swishf(float z) { return z * fastrcp(1.0f + __expf(-z)); }
__device__ __forceinline__ unsigned fbits(float x) { return __builtin_bit_cast(unsigned, x); }
__device__ __forceinline__ float ubf(unsigned x) { return __builtin_bit_cast(float, x); }

// Split a pair of f32 into packed bf16 hi (truncated) and bf16 lo (residual, truncated).
// 3-term MFMA (hi*hi + hi*lo + lo*hi) carries ~2^-16 relative error — fp32-fidelity here.
__device__ __forceinline__ void bfsplit2(float x0, float x1, unsigned& hi, unsigned& lo) {
  unsigned h0b = fbits(x0) & 0xffff0000u;
  unsigned h1b = fbits(x1) & 0xffff0000u;
  hi = (h0b >> 16) | h1b;
  float l0 = x0 - ubf(h0b), l1 = x1 - ubf(h1b);
  lo = (fbits(l0) >> 16) | (fbits(l1) & 0xffff0000u);
}

__global__ __launch_bounds__(256) void k_init(int* __restrict__ cnt, int* __restrict__ fill,
                                              float* __restrict__ stats) {
  int i = blockIdx.x * 256 + threadIdx.x;
  if (i < NSEG) { cnt[i] = 0; fill[i] = 0; }
  if (i < 8224) stats[i] = 0.0f;
}

// Pass 1: inv + cnt + feats moment matrix (S1[4], upper-tri S2[10]).
__global__ __launch_bounds__(256) void k_point1(const float* __restrict__ pts,
                                                int* __restrict__ inv,
                                                int* __restrict__ cnt,
                                                float* __restrict__ Sg) {
  float acc[14];
  #pragma unroll
  for (int q = 0; q < 14; ++q) acc[q] = 0.0f;
  const float i346 = 1.0f / 346.0f, i260 = 1.0f / 260.0f, i200 = 1.0f / 200.0f;
  const int stride = gridDim.x * 256;
  for (int i = blockIdx.x * 256 + threadIdx.x; i < NPTS; i += stride) {
    float b = pts[i*5];
    float4 v = *(const float4*)(pts + i*5 + 1);   // x,y,t,p (4B-aligned dwordx4)
    float x = v.x, y = v.y, t = v.z, p = v.w;
    // exact IEEE divide here: floor(RN(x/3)) must match jax at cell boundaries
    int cx = (int)floorf(x / 3.0f);
    int cy = (int)floorf(y / 3.0f);
    int bi = (int)b;
    if (cx >= 0 && cx < GXD && cy >= 0 && cy < GYD && bi >= 0 && bi < NB) {
      int iv = (bi*GXD + cx)*GYD + cy;
      inv[i] = iv;
      atomicAdd(&cnt[iv], 1);
    } else {
      inv[i] = -1;
    }
    float f0 = x*i346, f1 = y*i260, f2 = t*i200, f3 = p;
    acc[0]+=f0; acc[1]+=f1; acc[2]+=f2; acc[3]+=f3;
    acc[4]+=f0*f0; acc[5]+=f0*f1; acc[6]+=f0*f2; acc[7]+=f0*f3;
    acc[8]+=f1*f1; acc[9]+=f1*f2; acc[10]+=f1*f3;
    acc[11]+=f2*f2; acc[12]+=f2*f3; acc[13]+=f3*f3;
  }
  __shared__ float lds[4*14];
  int lane = threadIdx.x & 63, wave = threadIdx.x >> 6;
  #pragma unroll
  for (int q = 0; q < 14; ++q) {
    float v = acc[q];
    #pragma unroll
    for (int d = 32; d > 0; d >>= 1) v += __shfl_down(v, d, 64);
    if (lane == 0) lds[wave*14 + q] = v;
  }
  __syncthreads();
  if (threadIdx.x < 14) {
    float v = lds[threadIdx.x] + lds[14+threadIdx.x] + lds[28+threadIdx.x] + lds[42+threadIdx.x];
    atomicAdd(&Sg[threadIdx.x], v);
  }
}

// BN0 coefficients + W1 bf16 fragment precompute + exclusive scan of cnt -> offs.
__global__ __launch_bounds__(1024) void k_scan(const int* __restrict__ cnt,
                                               int* __restrict__ offs,
                                               const float* __restrict__ S,
                                               float* __restrict__ bn0,
                                               int4* __restrict__ frag,
                                               const float* __restrict__ W0,
                                               const float* __restrict__ g0,
                                               const float* __restrict__ b0,
                                               const float* __restrict__ W1) {
  __shared__ int wtot[16];
  const int tid = threadIdx.x;
  if (tid < 32) {
    const float invN = 1.0f / (float)NPTS;
    float w0 = W0[tid], w1 = W0[32+tid], w2 = W0[64+tid], w3 = W0[96+tid];
    float mu = (S[0]*w0 + S[1]*w1 + S[2]*w2 + S[3]*w3) * invN;
    float e2 = (S[4]*w0*w0 + S[8]*w1*w1 + S[11]*w2*w2 + S[13]*w3*w3
              + 2.0f*(S[5]*w0*w1 + S[6]*w0*w2 + S[7]*w0*w3
                    + S[9]*w1*w2 + S[10]*w1*w3 + S[12]*w2*w3)) * invN;
    float var = e2 - mu*mu;
    float a = rsqrtf(var + 1e-3f) * g0[tid];
    bn0[tid] = a;
    bn0[32+tid] = b0[tid] - mu*a;
  }
  // W1 fragments: FBH/FBL = top half rows 0..31 (hi/lo), FGH/FGL = bottom rows 32..63.
  // Fragment (t, lane): q=lane>>4, r=lane&15; word d packs rows (8q+2d, 8q+2d+1), col 16t+r.
  if (tid < 512) {
    const int t = tid >> 6, ln = tid & 63;
    const int qq = ln >> 4, rr = ln & 15;
    Frag fh, fl, gh, gl;
    #pragma unroll
    for (int d = 0; d < 4; ++d) {
      int row = 8*qq + 2*d, col = 16*t + rr;
      bfsplit2(W1[row*128 + col],      W1[(row+1)*128 + col],  fh.u[d], fl.u[d]);
      bfsplit2(W1[(32+row)*128 + col], W1[(33+row)*128 + col], gh.u[d], gl.u[d]);
    }
    frag[tid]        = fh.i4;
    frag[512 + tid]  = fl.i4;
    frag[1024 + tid] = gh.i4;
    frag[1536 + tid] = gl.i4;
  }
  const int CH = 40;                      // 1024*40 = 40960 >= NSEG
  const int base = tid * CH;
  int loc[CH];
  int s = 0;
  #pragma unroll
  for (int i = 0; i < CH; ++i) {
    int v = (base + i < NSEG) ? cnt[base + i] : 0;
    loc[i] = s; s += v;
  }
  int inc = s;
  const int lane = tid & 63, wv = tid >> 6;
  #pragma unroll
  for (int d = 1; d < 64; d <<= 1) {
    int t = __shfl_up(inc, d, 64);
    if (lane >= d) inc += t;
  }
  if (lane == 63) wtot[wv] = inc;
  __syncthreads();
  if (tid == 0) {
    int run = 0;
    #pragma unroll
    for (int w = 0; w < 16; ++w) { int t = wtot[w]; wtot[w] = run; run += t; }
    offs[NSEG] = run;
  }
  __syncthreads();
  int ex = wtot[wv] + (inc - s);          // exclusive prefix for this thread
  #pragma unroll
  for (int i = 0; i < CH; ++i)
    if (base + i < NSEG) offs[base + i] = ex + loc[i];
}

// Counting-sort scatter: writes the 16B point payload at its sorted position,
// so k_seg reads a fully-coalesced stream (no index->gather chain).
__global__ __launch_bounds__(256) void k_scatter(const float* __restrict__ pts,
                                                 const int* __restrict__ inv,
                                                 const int* __restrict__ offs,
                                                 int* __restrict__ fill,
                                                 float4* __restrict__ sp) {
  int i = blockIdx.x * 256 + threadIdx.x;
  if (i >= NPTS) return;
  int iv = inv[i];
  if (iv < 0) return;
  float4 v = *(const float4*)(pts + i*5 + 1);   // x,y,t,p
  int pos = offs[iv] + atomicAdd(&fill[iv], 1);
  sp[pos] = v;
}

// Main segment pass, MFMA version. Contiguous chunk of segments per wave,
// coalesced float4 point loads, precomputed W1 fragments.
// Lane l (q=l>>4, r=l&15):
//   A-fragment (mfma_f32_16x16x32_bf16): lane holds A[r][8q+j]  -> compute h0 of
//     point r, channels 8q..8q+7 directly in fragment layout.
//   B-fragment tile t: lane holds W1[8q+j][16t+r]. Bhi in VGPRs, Blo + bottom-W1
//     (hi/lo) in LDS.
//   D-fragment: lane holds z[point 4q+i][channel 16t+r] -> per-lane min/max/sum/ssq,
//     reduced across q via shfl_xor(16/32).
// minp/maxp stored CHANNEL-MAJOR [128][NSEG] so k_plane reads coalesced.
__global__ __launch_bounds__(256) void k_seg(const float4* __restrict__ sp,
                                             const int* __restrict__ offs,
                                             const float* __restrict__ W0,
                                             const float* __restrict__ bn0,
                                             const int4* __restrict__ frags,
                                             float* __restrict__ minp,
                                             float* __restrict__ maxp,
                                             float* __restrict__ stats) {
  __shared__ int4 fragLDS[1536];       // Blo | BBhi | BBlo  (24 KB)
  __shared__ float redS[4][16][16];    // wave, r, {8 gsum, 8 gssq}  (4 KB)
  const int tid = threadIdx.x;
  const int wave = tid >> 6, lane = tid & 63;
  const int q = lane >> 4, r = lane & 15;

  // B-hi fragments straight to VGPRs (coalesced dwordx4), rest to LDS.
  short8v Bhi[8];
  #pragma unroll
  for (int t = 0; t < 8; ++t) {
    Frag f; f.i4 = frags[t*64 + lane];
    Bhi[t] = f.v;
  }
  for (int i = tid; i < 1536; i += 256) fragLDS[i] = frags[512 + i];

  // per-lane BN0-folded W0 coefficients for channels 8q+j
  const float i346 = 1.0f/346.0f, i260 = 1.0f/260.0f, i200 = 1.0f/200.0f;
  float wax[8], way[8], wat[8], wap[8], wc0[8];
  #pragma unroll
  for (int j = 0; j < 8; ++j) {
    int ch = 8*q + j;
    float a0 = bn0[ch];
    wax[j] = W0[ch]    * (i346 * a0);
    way[j] = W0[32+ch] * (i260 * a0);
    wat[j] = W0[64+ch] * (i200 * a0);
    wap[j] = W0[96+ch] * a0;
    wc0[j] = bn0[32+ch];
  }
  __syncthreads();

  float gsum[8], gssq[8];
  #pragma unroll
  for (int t = 0; t < 8; ++t) { gsum[t] = 0.f; gssq[t] = 0.f; }

  // contiguous chunk of segments per wave (8192 waves total)
  const int w = blockIdx.x*4 + wave;
  const int qn = NSEG >> 13;                  // 4
  const int rm = NSEG - (qn << 13);           // 7600
  const int s0 = w*qn + (w < rm ? w : rm);
  const int scnt = qn + (w < rm ? 1 : 0);

  for (int s = s0; s < s0 + scnt; ++s) {
    const int off = offs[s], pend = offs[s+1];
    const int n = pend - off;
    if (n <= 0) continue;
    const int ngroups = (n + 15) >> 4;
    float m0r[8], mn[8], mx[8], su[8], sq[8];
    #pragma unroll
    for (int t = 0; t < 8; ++t) {
      m0r[t] = -1e30f; mn[t] = 1e30f; mx[t] = -1e30f; su[t] = 0.f; sq[t] = 0.f;
    }
    // group 0 point (slot r; pad slots replicate point 0 — min/max-safe)
    float4 P = sp[off + (r < n ? r : 0)];
    for (int g = 0; g < ngroups; ++g) {
      // prefetch next group's point (coalesced, no index chain)
      int slot1 = (g+1)*16 + r;
      float4 Pn = sp[off + (slot1 < n ? slot1 : 0)];

      // h0 for point r, channels 8q..8q+7 (exact A-fragment layout)
      float h0v[8];
      #pragma unroll
      for (int j = 0; j < 8; ++j) {
        float pre = fmaf(P.x, wax[j], fmaf(P.y, way[j], fmaf(P.z, wat[j], fmaf(P.w, wap[j], wc0[j]))));
        float h = swishf(pre);
        h0v[j] = h;
        m0r[j] = fmaxf(m0r[j], h);
      }
      Frag ah, al;
      #pragma unroll
      for (int d = 0; d < 4; ++d)
        bfsplit2(h0v[2*d], h0v[2*d+1], ah.u[d], al.u[d]);

      const int rem = n - g*16;
      #pragma unroll
      for (int t = 0; t < 8; ++t) {
        Frag fb; fb.i4 = fragLDS[t*64 + lane];
        float4v acc = {0.f, 0.f, 0.f, 0.f};
        acc = __builtin_amdgcn_mfma_f32_16x16x32_bf16(ah.v, Bhi[t], acc, 0, 0, 0);
        acc = __builtin_amdgcn_mfma_f32_16x16x32_bf16(ah.v, fb.v,   acc, 0, 0, 0);
        acc = __builtin_amdgcn_mfma_f32_16x16x32_bf16(al.v, Bhi[t], acc, 0, 0, 0);
        if (rem >= 16) {
          #pragma unroll
          for (int i = 0; i < 4; ++i) {
            float z = acc[i];
            mn[t] = fminf(mn[t], z); mx[t] = fmaxf(mx[t], z);
            su[t] += z; sq[t] = fmaf(z, z, sq[t]);
          }
        } else {
          // tail: min/max always safe (pad rows hold a real point's z);
          // sums gated per row (row = 4q+i)
          #pragma unroll
          for (int i = 0; i < 4; ++i) {
            float z = acc[i];
            mn[t] = fminf(mn[t], z); mx[t] = fmaxf(mx[t], z);
            float zz = (4*q + i < rem) ? z : 0.f;
            su[t] += zz; sq[t] = fmaf(zz, zz, sq[t]);
          }
        }
      }
      P = Pn;
    }

    // m0 = segment max of h0: reduce over r (bits 0..3 of lane)
    #pragma unroll
    for (int j = 0; j < 8; ++j) {
      float v = m0r[j];
      v = fmaxf(v, __shfl_xor(v, 1, 64));
      v = fmaxf(v, __shfl_xor(v, 2, 64));
      v = fmaxf(v, __shfl_xor(v, 4, 64));
      v = fmaxf(v, __shfl_xor(v, 8, 64));
      m0r[j] = v;
    }
    // c = m0 @ W1bot via MFMA; A rows all equal m0 -> every D reg holds c[16t+r]
    Frag mh, ml;
    #pragma unroll
    for (int d = 0; d < 4; ++d)
      bfsplit2(m0r[2*d], m0r[2*d+1], mh.u[d], ml.u[d]);
    float c[8];
    #pragma unroll
    for (int t = 0; t < 8; ++t) {
      Frag gh; gh.i4 = fragLDS[512 + t*64 + lane];
      Frag gl; gl.i4 = fragLDS[1024 + t*64 + lane];
      float4v cacc = {0.f, 0.f, 0.f, 0.f};
      cacc = __builtin_amdgcn_mfma_f32_16x16x32_bf16(mh.v, gh.v, cacc, 0, 0, 0);
      cacc = __builtin_amdgcn_mfma_f32_16x16x32_bf16(mh.v, gl.v, cacc, 0, 0, 0);
      cacc = __builtin_amdgcn_mfma_f32_16x16x32_bf16(ml.v, gh.v, cacc, 0, 0, 0);
      c[t] = cacc[0];
    }
    // combine across q-groups (xor 16, 32) -> full-segment values on all lanes
    #pragma unroll
    for (int t = 0; t < 8; ++t) {
      mn[t] = fminf(mn[t], __shfl_xor(mn[t], 16, 64));
      mn[t] = fminf(mn[t], __shfl_xor(mn[t], 32, 64));
      mx[t] = fmaxf(mx[t], __shfl_xor(mx[t], 16, 64));
      mx[t] = fmaxf(mx[t], __shfl_xor(mx[t], 32, 64));
      su[t] += __shfl_xor(su[t], 16, 64);
      su[t] += __shfl_xor(su[t], 32, 64);
      sq[t] += __shfl_xor(sq[t], 16, 64);
      sq[t] += __shfl_xor(sq[t], 32, 64);
      float nf = (float)n;
      gsum[t] += su[t] + nf * c[t];
      gssq[t] += sq[t] + 2.0f*c[t]*su[t] + nf*c[t]*c[t];
    }
    if (lane < 16) {
      #pragma unroll
      for (int t = 0; t < 8; ++t) {
        minp[(16*t + r)*NSEG + s] = mn[t] + c[t];
        maxp[(16*t + r)*NSEG + s] = mx[t] + c[t];
      }
    }
  }
  // block-level reduction of BN1-stat partials, then sharded atomics (16 copies)
  if (lane < 16) {
    #pragma unroll
    for (int t = 0; t < 8; ++t) {
      redS[wave][r][t]     = gsum[t];
      redS[wave][r][8 + t] = gssq[t];
    }
  }
  __syncthreads();
  if (wave == 0 && lane < 16) {
    const int cpy = blockIdx.x & 15;
    float* sb = stats + 16 + 512*cpy;
    #pragma unroll
    for (int t = 0; t < 8; ++t) {
      float s0v = redS[0][r][t]   + redS[1][r][t]   + redS[2][r][t]   + redS[3][r][t];
      float q0v = redS[0][r][8+t] + redS[1][r][8+t] + redS[2][r][8+t] + redS[3][r][8+t];
      atomicAdd(&sb[16*t + r], s0v);
      atomicAdd(&sb[256 + 16*t + r], q0v);
    }
  }
}

// Fused dense+resize: one block per (b, channel). Builds the 87x116 plane in LDS
// (BN1 + swish at pre-extremes; exact segment_max via swish quasiconvexity), then
// emits the bilinear-resized 224x224 plane directly. Eliminates the dense
// intermediate (42 MB traffic) and a kernel launch.
__global__ __launch_bounds__(256) void k_plane(const float* __restrict__ minp,
                                               const float* __restrict__ maxp,
                                               const int* __restrict__ offs,
                                               const float* __restrict__ stats,
                                               const float* __restrict__ g1,
                                               const float* __restrict__ b1,
                                               float* __restrict__ out) {
  __shared__ float plane[87*117];     // pitch 117: stride-117 writes are ~conflict-free
  __shared__ float ab[2];
  const int c = blockIdx.x & 127;
  const int b = blockIdx.x >> 7;
  const int tid = threadIdx.x;
  if (tid == 0) {
    float s = 0.f, q2 = 0.f;
    #pragma unroll
    for (int cpy = 0; cpy < 16; ++cpy) {
      s  += stats[16 + 512*cpy + c];
      q2 += stats[16 + 512*cpy + 256 + c];
    }
    const float invN = 1.0f / (float)NPTS;
    float mu = s * invN;
    float var = q2 * invN - mu*mu;
    float a = rsqrtf(var + 1e-3f) * g1[c];
    ab[0] = a;
    ab[1] = b1[c] - mu*a;
  }
  __syncthreads();
  const float a = ab[0], bb = ab[1];
  const int sBase = b * (GXD*GYD);
  const float* mnp = minp + c*NSEG + sBase;   // coalesced channel-major reads
  const float* mxp = maxp + c*NSEG + sBase;
  for (int i = tid; i < GXD*GYD; i += 256) {
    int gx = i / GYD, gy = i - gx*GYD;
    float m = 0.0f;
    int s = sBase + i;
    if (offs[s+1] - offs[s] > 0) {
      float zl = fmaf(a, mnp[i], bb);
      float zh = fmaf(a, mxp[i], bb);
      m = fmaxf(swishf(zl), swishf(zh));
    }
    plane[gy*117 + gx] = m;
  }
  __syncthreads();
  float* op = out + (size_t)blockIdx.x * (224*224);
  for (int o4 = tid; o4 < 224*56; o4 += 256) {
    int xq = o4 % 56;
    int yo = o4 / 56;
    float ys = (float)yo * (86.0f/223.0f);
    float yf = floorf(ys); int y0 = (int)yf; int y1 = min(y0+1, 86); float wy = ys - yf;
    const float* p0 = plane + y0*117;
    const float* p1 = plane + y1*117;
    float res[4];
    #pragma unroll
    for (int gph = 0; gph < 4; ++gph) {
      int xo = xq*4 + gph;
      float xs = (float)xo * (115.0f/223.0f);
      float xf = floorf(xs); int x0 = (int)xf; int x1 = min(x0+1, 115); float wx = xs - xf;
      float c0v = p0[x0]*(1.0f-wy) + p1[x0]*wy;
      float c1v = p0[x1]*(1.0f-wy) + p1[x1]*wy;
      res[gph] = c0v*(1.0f-wx) + c1v*wx;
    }
    *(float4*)&op[yo*224 + xq*4] = make_float4(res[0], res[1], res[2], res[3]);
  }
}

extern "C" void kernel_launch(void* const* d_in, const int* in_sizes, int n_in,
                              void* d_out, int out_size, void* d_ws, size_t ws_size,
                              hipStream_t stream) {
  // setup_inputs order: fus(unused), points, W0, g0, b0, W1, g1, b1
  const float* pts = (const float*)d_in[1];
  const float* W0  = (const float*)d_in[2];
  const float* g0  = (const float*)d_in[3];
  const float* b0  = (const float*)d_in[4];
  const float* W1  = (const float*)d_in[5];
  const float* g1  = (const float*)d_in[6];
  const float* b1  = (const float*)d_in[7];
  float* out = (float*)d_out;
  int*   wsi = (int*)d_ws;
  float* wsf = (float*)d_ws;

  k_init<<<158, 256, 0, stream>>>(wsi+OFF_CNT, wsi+OFF_FILL, wsf+OFF_STATS);
  k_point1<<<256, 256, 0, stream>>>(pts, wsi+OFF_INV, wsi+OFF_CNT, wsf+OFF_STATS);
  k_scan<<<1, 1024, 0, stream>>>(wsi+OFF_CNT, wsi+OFF_OFFS, wsf+OFF_STATS, wsf+OFF_BN0,
                                 (int4*)(wsf+OFF_FRAG), W0, g0, b0, W1);
  k_scatter<<<(NPTS+255)/256, 256, 0, stream>>>(pts, wsi+OFF_INV, wsi+OFF_OFFS,
                                                wsi+OFF_FILL, (float4*)(wsf+OFF_SPTS));
  k_seg<<<2048, 256, 0, stream>>>((const float4*)(wsf+OFF_SPTS), wsi+OFF_OFFS, W0,
                                  wsf+OFF_BN0, (const int4*)(wsf+OFF_FRAG),
                                  wsf+OFF_MINP, wsf+OFF_MAXP, wsf+OFF_STATS);
  k_plane<<<NB*128, 256, 0, stream>>>(wsf+OFF_MINP, wsf+OFF_MAXP, wsi+OFF_OFFS,
                                      wsf+OFF_STATS, g1, b1, out);
}